// Round 23
// baseline (84.943 us; speedup 1.0000x reference)
//
#include <hip/hip_runtime.h>

// LIF neuron scan: v = v*0.5 + x[t]; s = (v - 0.5 > 0); v -= s*0.5
// Round 22 -> 23: INTRA-BLOCK SUB-TILE PIPELINE (the last untried overlap
// mechanism). Row-major LDS forces a full vmcnt(0) before the walk (walk's
// first ds_read spans ALL chunks), so each wave's read stream goes dark for
// walk+store; inter-block stagger (R21/R22) only partially covers it and is
// saturating (84.7 -> 83.2 -> 82.4 for 6/8/12 blocks per CU). Fix while
// KEEPING coalesced DMA: two independent 16-row half-tiles per block.
//   issue 7 DMA (A) + 7 DMA (B)        [14 VMEM in flight]
//   vmcnt(7)  -> A arrived, B STILL IN FLIGHT
//   walk A (lanes 0-15) -> bits -> 7 coalesced stores (A)
//   vmcnt(7)  -> 7 newest = A-stores; forces older B-DMA retired
//   walk B -> bits -> 7 coalesced stores (B)
// B's arrival hides under walk A + store A within every block, stacked on
// the 12-blocks/CU stagger. LDS 2x6.4KB + 256B = 13.1KB -> 12 blocks/CU.
// 16-lane walk: quad (25*lane+c)%8 hits each group 2x = free (m136).
// bits ordering: in-wave DS pipe + sched_barrier(0), zero __syncthreads
// (no hidden vmcnt drains) -- the R19/R20-proven (bit-exact) pattern.

#define T_STEPS 100
#define T_VEC   25                  // f4 per row
#define ROWS    32                  // rows per block
#define HR      16                  // rows per half-tile
#define HF4     (HR * T_VEC)        // 400 f4 = 6.4 KB
#define NDMA    7                   // ceil(400/64); last chunk 16 lanes
#define DECAY   0.5f
#define VTH     0.5f

typedef float vfloat4 __attribute__((ext_vector_type(4)));

__device__ __forceinline__ void gll16(const vfloat4* g, vfloat4* l) {
    // DMA 16B/lane: LDS dest = wave-uniform l + lane*16; global src per-lane.
    __builtin_amdgcn_global_load_lds(
        (const __attribute__((address_space(1))) void*)g,
        (__attribute__((address_space(3))) void*)l, 16, 0, 0);
}

__global__ __launch_bounds__(64) void lif_gll2h(const float* __restrict__ x,
                                                float* __restrict__ out,
                                                int n_rows) {
    __shared__ vfloat4 tileA[HF4];   // 6,400 B
    __shared__ vfloat4 tileB[HF4];   // 6,400 B
    __shared__ uint4   bits[HR];     //   256 B -> 13,056 total: 12 blocks/CU

    const int lane = threadIdx.x;
    const long long row0 = (long long)blockIdx.x * ROWS;
    const long long gf0  = row0 * T_VEC;         // half A global f4 base
    const long long gf1  = gf0 + HF4;            // half B global f4 base
    const long long total_f4 = (long long)n_rows * T_VEC;

    const vfloat4* __restrict__ xb = reinterpret_cast<const vfloat4*>(x);
    vfloat4* __restrict__ ob       = reinterpret_cast<vfloat4*>(out);
    const unsigned int* bw = reinterpret_cast<const unsigned int*>(bits);

    // ---- Issue ALL 14 DMA: half A then half B (order = vmcnt order) ----
    #pragma unroll
    for (int k = 0; k < NDMA; ++k) {
        int f = k * 64 + lane;
        if (f < HF4 && gf0 + f < total_f4) gll16(xb + (gf0 + f), &tileA[k * 64]);
    }
    #pragma unroll
    for (int k = 0; k < NDMA; ++k) {
        int f = k * 64 + lane;
        if (f < HF4 && gf1 + f < total_f4) gll16(xb + (gf1 + f), &tileB[k * 64]);
    }
    __builtin_amdgcn_sched_barrier(0);
    // Retire A's 7 DMA; B's 7 stay in flight under walk A + store A.
    asm volatile("s_waitcnt vmcnt(7)" ::: "memory");
    __builtin_amdgcn_sched_barrier(0);

    // ---- Walk A: lanes 0..15 (rows row0..row0+15), pack spike bits ----
    if (lane < HR && row0 + lane < n_rows) {
        unsigned int pk0 = 0, pk1 = 0, pk2 = 0, pk3 = 0;
        float v = 0.0f;
        #pragma unroll
        for (int c = 0; c < T_VEC; ++c) {
            vfloat4 xs = tileA[lane * T_VEC + c];
            #pragma unroll
            for (int k = 0; k < 4; ++k) {
                // v*0.5 exact (pow2); conditional -0.5 exact -> bitwise == ref.
                v = v * DECAY + xs[k];
                bool sp = (v - VTH > 0.0f);
                v -= sp ? VTH : 0.0f;
                unsigned int bit = sp ? 1u : 0u;
                const int b = c * 4 + k;               // compile-time 0..99
                if      (b < 32) pk0 |= bit << b;
                else if (b < 64) pk1 |= bit << (b - 32);
                else if (b < 96) pk2 |= bit << (b - 64);
                else             pk3 |= bit << (b - 96);
            }
        }
        uint4 w; w.x = pk0; w.y = pk1; w.z = pk2; w.w = pk3;
        bits[lane] = w;
    }
    __builtin_amdgcn_sched_barrier(0);   // pin bits ds_write before expand reads

    // ---- Expand + store A: 7 coalesced full-line stores ----
    #pragma unroll
    for (int i = 0; i < NDMA; ++i) {
        int f = i * 64 + lane;                         // 0..447
        long long g = gf0 + f;
        if (f < HF4 && g < total_f4) {
            int r  = f / T_VEC;                        // 0..15, magic-mul
            int c4 = f % T_VEC;
            unsigned int word = bw[r * 4 + (c4 >> 3)];
            unsigned int nib = (word >> ((c4 & 7) * 4)) & 0xFu;
            vfloat4 s;
            s.x = (nib & 1u) ? 1.0f : 0.0f;
            s.y = (nib & 2u) ? 1.0f : 0.0f;
            s.z = (nib & 4u) ? 1.0f : 0.0f;
            s.w = (nib & 8u) ? 1.0f : 0.0f;
            ob[g] = s;
        }
    }
    __builtin_amdgcn_sched_barrier(0);
    // 7 newest outstanding = A's stores; forces B's older DMA retired.
    asm volatile("s_waitcnt vmcnt(7)" ::: "memory");
    __builtin_amdgcn_sched_barrier(0);

    // ---- Walk B: lanes 0..15 (rows row0+16..row0+31) ----
    if (lane < HR && row0 + HR + lane < n_rows) {
        unsigned int pk0 = 0, pk1 = 0, pk2 = 0, pk3 = 0;
        float v = 0.0f;
        #pragma unroll
        for (int c = 0; c < T_VEC; ++c) {
            vfloat4 xs = tileB[lane * T_VEC + c];
            #pragma unroll
            for (int k = 0; k < 4; ++k) {
                v = v * DECAY + xs[k];
                bool sp = (v - VTH > 0.0f);
                v -= sp ? VTH : 0.0f;
                unsigned int bit = sp ? 1u : 0u;
                const int b = c * 4 + k;
                if      (b < 32) pk0 |= bit << b;
                else if (b < 64) pk1 |= bit << (b - 32);
                else if (b < 96) pk2 |= bit << (b - 64);
                else             pk3 |= bit << (b - 96);
            }
        }
        uint4 w; w.x = pk0; w.y = pk1; w.z = pk2; w.w = pk3;
        bits[lane] = w;     // in-order DS: expand-A's bits reads already done
    }
    __builtin_amdgcn_sched_barrier(0);

    // ---- Expand + store B ----
    #pragma unroll
    for (int i = 0; i < NDMA; ++i) {
        int f = i * 64 + lane;
        long long g = gf1 + f;
        if (f < HF4 && g < total_f4) {
            int r  = f / T_VEC;
            int c4 = f % T_VEC;
            unsigned int word = bw[r * 4 + (c4 >> 3)];
            unsigned int nib = (word >> ((c4 & 7) * 4)) & 0xFu;
            vfloat4 s;
            s.x = (nib & 1u) ? 1.0f : 0.0f;
            s.y = (nib & 2u) ? 1.0f : 0.0f;
            s.z = (nib & 4u) ? 1.0f : 0.0f;
            s.w = (nib & 8u) ? 1.0f : 0.0f;
            ob[g] = s;
        }
    }
}

extern "C" void kernel_launch(void* const* d_in, const int* in_sizes, int n_in,
                              void* d_out, int out_size, void* d_ws, size_t ws_size,
                              hipStream_t stream) {
    const float* x = (const float*)d_in[0];
    float* out = (float*)d_out;

    int n_rows = in_sizes[0] / T_STEPS;              // 32 * 16384 = 524288
    int grid = (n_rows + ROWS - 1) / ROWS;           // 16384

    lif_gll2h<<<grid, 64, 0, stream>>>(x, out, n_rows);
}